// Round 7
// baseline (554.265 us; speedup 1.0000x reference)
//
#include <hip/hip_runtime.h>

#define N_NODES 100000
#define N_EDGES 1600000
#define CH      128
#define OUT_CH  64
#define NUM_G   64
#define NREP    8           // replicas (XCD-aligned via blockIdx&7)

typedef unsigned short ushort_t;
typedef unsigned int uint_t;
typedef __attribute__((ext_vector_type(8))) short short8;
typedef __attribute__((ext_vector_type(4))) float f32x4;

#define WB 64               // cvt_w blocks per weight (128*128/256)
#define EB 6250             // edge blocks, 1 edge/thread (prep)
#define EB8 782             // edge blocks, 8 edges/thread (fill)
#define GB ((N_NODES + 63) / 64)     // fill-gemm row-blocks (64 rows/block)
#define GB2 ((N_NODES + 127) / 128)  // lds-gemm row-blocks (128 rows/block)
#define AB ((N_NODES + 3) / 4)       // agg node-quads (4 nodes/block)
#define AB2 (AB * 2)                 // channel-split agg blocks (x2 halves)
#define SB 98               // scan blocks (ceil(100000/1024))

__device__ __forceinline__ ushort_t f2b(float f) {
    union { float f; uint_t i; } v; v.f = f;
    uint_t u = v.i;
    uint_t r = (u + 0x7fffu + ((u >> 16) & 1u)) >> 16;
    return (ushort_t)r;
}
__device__ __forceinline__ float blo(uint_t u) {
    union { uint_t i; float f; } v; v.i = u << 16; return v.f;
}
__device__ __forceinline__ float bhi(uint_t u) {
    union { uint_t i; float f; } v; v.i = u & 0xffff0000u; return v.f;
}

// ---------------- fused prep: count_deg(+pos, 8-way replicated) | cvt_w x3 ----
__global__ __launch_bounds__(256) void prep_kernel(const float* __restrict__ W1,
                                                   const float* __restrict__ W2,
                                                   const float* __restrict__ W3,
                                                   ushort_t* __restrict__ Wt1,
                                                   ushort_t* __restrict__ Wt2,
                                                   ushort_t* __restrict__ Wt3,
                                                   const int* __restrict__ dst,
                                                   int* __restrict__ cnt8,
                                                   int* __restrict__ pos) {
    int b = blockIdx.x, tid = threadIdx.x;
    if (b < EB) {
        int e = b * 256 + tid;
        if (e < N_EDGES) {
            int r = b & (NREP - 1);            // == (e>>8)&7
            pos[e] = atomicAdd(&cnt8[(size_t)r * N_NODES + dst[e]], 1);
        }
    } else {
        int wi = (b - EB) / WB;
        const float* W  = (wi == 0) ? W1 : (wi == 1) ? W2 : W3;
        ushort_t*   Wt = (wi == 0) ? Wt1 : (wi == 1) ? Wt2 : Wt3;
        int t = ((b - EB) % WB) * 256 + tid;
        int k = t >> 7, n = t & 127;
        Wt[(size_t)n * CH + k] = f2b(W[t]);
    }
}

// ---------------- 3-phase scan (+dinv + replica fold + graph counts) ---------
__device__ __forceinline__ int wave_incl_scan(int v, int lane) {
#pragma unroll
    for (int off = 1; off < 64; off <<= 1) {
        int t = __shfl_up(v, off);
        if (lane >= off) v += t;
    }
    return v;
}

__global__ __launch_bounds__(1024) void scan_p1(int* __restrict__ cnt8,
                                                int* __restrict__ ptr,
                                                int* __restrict__ bsum,
                                                float* __restrict__ dinv,
                                                const int* __restrict__ batch,
                                                int* __restrict__ counts) {
    __shared__ int s_w[16];
    __shared__ int s_c[NUM_G];
    int tid = threadIdx.x, lane = tid & 63, wid = tid >> 6;
    int i = blockIdx.x * 1024 + tid;
    int v = 0;
    if (i < N_NODES) {
        // fold 8 replicas -> total; store per-replica EXCLUSIVE offsets in place
        int run = 0;
#pragma unroll
        for (int r = 0; r < NREP; ++r) {
            size_t idx = (size_t)r * N_NODES + i;
            int t = cnt8[idx];
            cnt8[idx] = run;
            run += t;
        }
        v = run;
        dinv[i] = rsqrtf((float)v + 1.0f);
    }
    int incl = wave_incl_scan(v, lane);
    if (lane == 63) s_w[wid] = incl;
    if (tid < NUM_G) s_c[tid] = 0;
    __syncthreads();
    if (tid < 16) {
        int w = s_w[tid];
#pragma unroll
        for (int off = 1; off < 16; off <<= 1) {
            int t = __shfl_up(w, off);
            if (tid >= off) w += t;
        }
        s_w[tid] = w;
    }
    if (i < N_NODES) atomicAdd(&s_c[batch[i]], 1);   // graph-size histogram
    __syncthreads();
    int woff = (wid > 0) ? s_w[wid - 1] : 0;
    if (i < N_NODES) ptr[i] = woff + incl - v;     // block-local exclusive
    if (tid == 0) bsum[blockIdx.x] = s_w[15];
    if (tid < NUM_G) atomicAdd(&counts[tid], s_c[tid]);
}

__global__ __launch_bounds__(128) void scan_p2(const int* __restrict__ bsum,
                                               int* __restrict__ boff,
                                               int* __restrict__ ptr) {
    __shared__ int s_w[2];
    int tid = threadIdx.x, lane = tid & 63, wid = tid >> 6;
    int v = (tid < SB) ? bsum[tid] : 0;
    int incl = wave_incl_scan(v, lane);
    if (lane == 63) s_w[wid] = incl;
    __syncthreads();
    int woff = (wid == 1) ? s_w[0] : 0;
    int excl = woff + incl - v;
    if (tid < SB) boff[tid] = excl;
    if (tid == SB - 1) ptr[N_NODES] = excl + v;
}

// phase 3: finalize ptr AND fold final ptr into every cnt8 replica, so the
// fill kernel needs a single random read (cnt8[r][d] = ptr_final[d]+excl_r[d]).
__global__ __launch_bounds__(1024) void scan_p3(int* __restrict__ ptr,
                                                const int* __restrict__ boff,
                                                int* __restrict__ cnt8) {
    int i = blockIdx.x * 1024 + threadIdx.x;
    if (i < N_NODES) {
        int fp = ptr[i] + boff[blockIdx.x];
        ptr[i] = fp;
#pragma unroll
        for (int r = 0; r < NREP; ++r)
            cnt8[(size_t)r * N_NODES + i] += fp;
    }
}

// ---------------- MFMA GEMM body, global-Wt flavor (used inside fill) --------
template <bool F32A>
__device__ __forceinline__ void gemm_body(int bid, int tid,
                                          const void* __restrict__ A,
                                          const ushort_t* __restrict__ Wt,
                                          const float* __restrict__ bias,
                                          ushort_t* __restrict__ H) {
    int wv = tid >> 6, lane = tid & 63;
    int q = lane >> 4, ml = lane & 15;
    int r0 = bid * 64 + wv * 16;
    int arow = r0 + ml;
    if (arow >= N_NODES) arow = N_NODES - 1;  // clamp; stores guarded

    f32x4 acc[8];
#pragma unroll
    for (int ct = 0; ct < 8; ++ct) { acc[ct][0] = 0.f; acc[ct][1] = 0.f; acc[ct][2] = 0.f; acc[ct][3] = 0.f; }

#pragma unroll
    for (int ks = 0; ks < 4; ++ks) {
        short8 af;
        if constexpr (F32A) {
            const float* ap = (const float*)A + (size_t)arow * CH + ks * 32 + q * 8;
            f32x4 v0 = *(const f32x4*)ap;
            f32x4 v1 = *(const f32x4*)(ap + 4);
#pragma unroll
            for (int j = 0; j < 4; ++j) {
                af[j]     = (short)f2b(v0[j]);
                af[j + 4] = (short)f2b(v1[j]);
            }
        } else {
            const ushort_t* ap = (const ushort_t*)A + (size_t)arow * CH + ks * 32 + q * 8;
            af = *(const short8*)ap;
        }
#pragma unroll
        for (int ct = 0; ct < 8; ++ct) {
            short8 bf = *(const short8*)(Wt + (size_t)(ct * 16 + ml) * CH + ks * 32 + q * 8);
            acc[ct] = __builtin_amdgcn_mfma_f32_16x16x32_bf16(af, bf, acc[ct], 0, 0, 0);
        }
    }

#pragma unroll
    for (int ct = 0; ct < 8; ++ct) {
        int col = ct * 16 + ml;
        float bv = bias[col];
#pragma unroll
        for (int i = 0; i < 4; ++i) {
            int rr = r0 + q * 4 + i;
            if (rr < N_NODES)
                H[(size_t)rr * CH + col] = f2b(acc[ct][i] + bv);
        }
    }
}

// ---------------- fused: CSR fill (8 edges/thread) | gemm layer-1 (fp32 A) ---
__global__ __launch_bounds__(256) void fill_gemm1(const int* __restrict__ src,
                                                  const int* __restrict__ dst,
                                                  const int* __restrict__ pos,
                                                  const int* __restrict__ cnt8,
                                                  int* __restrict__ csr_src,
                                                  const float* __restrict__ x,
                                                  const ushort_t* __restrict__ Wt,
                                                  const float* __restrict__ bias,
                                                  ushort_t* __restrict__ H) {
    if (blockIdx.x < EB8) {
        int e = (blockIdx.x * 256 + threadIdx.x) * 8;
        if (e < N_EDGES) {     // N_EDGES % 8 == 0; 8-aligned e never crosses 256
            const int* base = cnt8 + (size_t)((e >> 8) & (NREP - 1)) * N_NODES;
            int4 da = *(const int4*)(dst + e);
            int4 db = *(const int4*)(dst + e + 4);
            int4 pa = *(const int4*)(pos + e);
            int4 pb = *(const int4*)(pos + e + 4);
            int4 sa = *(const int4*)(src + e);
            int4 sb = *(const int4*)(src + e + 4);
            csr_src[base[da.x] + pa.x] = sa.x;
            csr_src[base[da.y] + pa.y] = sa.y;
            csr_src[base[da.z] + pa.z] = sa.z;
            csr_src[base[da.w] + pa.w] = sa.w;
            csr_src[base[db.x] + pb.x] = sb.x;
            csr_src[base[db.y] + pb.y] = sb.y;
            csr_src[base[db.z] + pb.z] = sb.z;
            csr_src[base[db.w] + pb.w] = sb.w;
        }
    } else {
        gemm_body<true>(blockIdx.x - EB8, threadIdx.x, x, Wt, bias, H);
    }
}

// ---------------- standalone GEMM: Wt staged in LDS (XOR-swizzled) -----------
__global__ __launch_bounds__(512) void gemm_mfma(const ushort_t* __restrict__ A,
                                                 const ushort_t* __restrict__ Wt,
                                                 const float* __restrict__ bias,
                                                 ushort_t* __restrict__ H) {
    __shared__ ushort_t sW[CH * CH];   // 32 KiB
    int tid = threadIdx.x;
    for (int i = tid; i < CH * CH / 8; i += 512) {   // 2048 x 16B chunks
        int row = i >> 4, slot = i & 15;
        uint4 v = *(const uint4*)(Wt + (size_t)row * CH + slot * 8);
        *(uint4*)(&sW[row * CH + ((slot ^ (row & 7)) * 8)]) = v;
    }
    __syncthreads();

    int wv = tid >> 6, lane = tid & 63;
    int q = lane >> 4, ml = lane & 15;
    int r0 = blockIdx.x * 128 + wv * 16;
    int arow = r0 + ml;
    if (arow >= N_NODES) arow = N_NODES - 1;
    const ushort_t* ap = A + (size_t)arow * CH;

    f32x4 acc[8];
#pragma unroll
    for (int ct = 0; ct < 8; ++ct) { acc[ct][0] = 0.f; acc[ct][1] = 0.f; acc[ct][2] = 0.f; acc[ct][3] = 0.f; }

#pragma unroll
    for (int ks = 0; ks < 4; ++ks) {
        short8 af = *(const short8*)(ap + ks * 32 + q * 8);
        int slot = ks * 4 + q;
#pragma unroll
        for (int ct = 0; ct < 8; ++ct) {
            int srow = ct * 16 + ml;
            short8 bf = *(const short8*)(&sW[srow * CH + ((slot ^ (srow & 7)) * 8)]);
            acc[ct] = __builtin_amdgcn_mfma_f32_16x16x32_bf16(af, bf, acc[ct], 0, 0, 0);
        }
    }

#pragma unroll
    for (int ct = 0; ct < 8; ++ct) {
        int col = ct * 16 + ml;
        float bv = bias[col];
#pragma unroll
        for (int i = 0; i < 4; ++i) {
            int rr = r0 + q * 4 + i;
            if (rr < N_NODES)
                H[(size_t)rr * CH + col] = f2b(acc[ct][i] + bv);
        }
    }
}

// ---------------- channel-split gather body (64 ch = one 128-B line) ---------
// 8-lane channel groups x 8 edge slots per wave. cb = half*64 + (lane&7)*8,
// cg = lane>>3. Each XCD only ever touches one 128-B half of every row.
__device__ __forceinline__ void agg_node_h(int node, int lane, int cg, int cb,
                                           const ushort_t* __restrict__ h,
                                           const int* __restrict__ csr_src,
                                           const int* __restrict__ ptr,
                                           const float* __restrict__ dinv,
                                           float (&acc)[8]) {
    int beg = ptr[node], end = ptr[node + 1];
    float dn = dinv[node];
    uint4 us = *(const uint4*)(h + (size_t)node * CH + cb);   // early self load
#pragma unroll
    for (int i = 0; i < 8; ++i) acc[i] = 0.0f;

    for (int e0 = beg; e0 < end; e0 += 64) {
        int e = e0 + lane;
        int s = 0; float w = 0.0f;
        if (e < end) { s = csr_src[e]; w = dinv[s]; }
        int m = min(64, end - e0);

        int   sj = __shfl(s, cg);
        float wj = __shfl(w, cg);
        uint4 u  = *(const uint4*)(h + (size_t)sj * CH + cb);

        for (int j0 = 0; j0 < m; j0 += 8) {
            uint4 un = u; float wn = 0.0f;
            if (j0 + 8 < m) {                      // max shfl idx 56+7=63, safe
                int sn = __shfl(s, j0 + 8 + cg);
                wn = __shfl(w, j0 + 8 + cg);
                un = *(const uint4*)(h + (size_t)sn * CH + cb);
            }
            acc[0] = fmaf(wj, blo(u.x), acc[0]);
            acc[1] = fmaf(wj, bhi(u.x), acc[1]);
            acc[2] = fmaf(wj, blo(u.y), acc[2]);
            acc[3] = fmaf(wj, bhi(u.y), acc[3]);
            acc[4] = fmaf(wj, blo(u.z), acc[4]);
            acc[5] = fmaf(wj, bhi(u.z), acc[5]);
            acc[6] = fmaf(wj, blo(u.w), acc[6]);
            acc[7] = fmaf(wj, bhi(u.w), acc[7]);
            u = un; wj = wn;
        }
    }

#pragma unroll
    for (int i = 0; i < 8; ++i) {          // sum over the 8 edge-slot groups
        acc[i] += __shfl_xor(acc[i], 8);
        acc[i] += __shfl_xor(acc[i], 16);
        acc[i] += __shfl_xor(acc[i], 32);
    }

    acc[0] = dn * fmaf(dn, blo(us.x), acc[0]);
    acc[1] = dn * fmaf(dn, bhi(us.x), acc[1]);
    acc[2] = dn * fmaf(dn, blo(us.y), acc[2]);
    acc[3] = dn * fmaf(dn, bhi(us.y), acc[3]);
    acc[4] = dn * fmaf(dn, blo(us.z), acc[4]);
    acc[5] = dn * fmaf(dn, bhi(us.z), acc[5]);
    acc[6] = dn * fmaf(dn, blo(us.w), acc[6]);
    acc[7] = dn * fmaf(dn, bhi(us.w), acc[7]);
}

// block -> (half, node-quad): half=(b>>2)&1 so (blockIdx%8) round-robin keeps
// XCDs 0-3 on channel-half 0 and XCDs 4-7 on half 1 (perf-only assumption).
__device__ __forceinline__ void split_decode(int b, int wv,
                                             int& half, int& node) {
    half = (b >> 2) & 1;
    int nb = ((b >> 3) << 2) | (b & 3);     // [0, AB)
    node = nb * 4 + wv;
}

// ---------------- edge aggregation, layers 1&2 (writes bf16 + relu) ----------
__global__ __launch_bounds__(256) void agg_bf16(const ushort_t* __restrict__ h,
                                                const int* __restrict__ csr_src,
                                                const int* __restrict__ ptr,
                                                const float* __restrict__ dinv,
                                                ushort_t* __restrict__ outp) {
    int wv = threadIdx.x >> 6, lane = threadIdx.x & 63;
    int half, node;
    split_decode(blockIdx.x, wv, half, node);
    if (node >= N_NODES) return;
    int cg = lane >> 3;
    int cb = half * 64 + (lane & 7) * 8;

    float acc[8];
    agg_node_h(node, lane, cg, cb, h, csr_src, ptr, dinv, acc);

#pragma unroll
    for (int i = 0; i < 8; ++i) acc[i] = fmaxf(acc[i], 0.0f);   // relu

    if (cg == 0) {
        uint4 o;
        o.x = (uint_t)f2b(acc[0]) | ((uint_t)f2b(acc[1]) << 16);
        o.y = (uint_t)f2b(acc[2]) | ((uint_t)f2b(acc[3]) << 16);
        o.z = (uint_t)f2b(acc[4]) | ((uint_t)f2b(acc[5]) << 16);
        o.w = (uint_t)f2b(acc[6]) | ((uint_t)f2b(acc[7]) << 16);
        *(uint4*)(outp + (size_t)node * CH + cb) = o;
    }
}

// ---------------- layer-3 aggregation fused with mean-pool -------------------
// Pool into 8 XCD-replicated global f32 buffers, 1 fire-and-forget atomic per
// lane (the 8 group-copies each take one of the lane's 8 channels).
__global__ __launch_bounds__(256) void agg_pool(const ushort_t* __restrict__ h,
                                                const int* __restrict__ csr_src,
                                                const int* __restrict__ ptr,
                                                const float* __restrict__ dinv,
                                                const int* __restrict__ batch,
                                                float* __restrict__ gsums) {
    int wv = threadIdx.x >> 6, lane = threadIdx.x & 63;
    int half, node;
    split_decode(blockIdx.x, wv, half, node);
    if (node >= N_NODES) return;
    int cg = lane >> 3;
    int cb = half * 64 + (lane & 7) * 8;

    float acc[8];
    agg_node_h(node, lane, cg, cb, h, csr_src, ptr, dinv, acc);  // no relu

    // static-index select of acc[cg] (avoid runtime-indexed array -> scratch)
    float val = acc[0];
#pragma unroll
    for (int t = 1; t < 8; ++t) if (cg == t) val = acc[t];

    int g = batch[node];
    unsafeAtomicAdd(gsums + (size_t)(blockIdx.x & (NREP - 1)) * (NUM_G * CH)
                          + g * CH + cb + cg, val);
}

// ---------------- final: fold 8 replicas, mean, @ Wp + bp --------------------
__global__ __launch_bounds__(128) void out_kernel(const float* __restrict__ gsums,
                                                  const int* __restrict__ counts,
                                                  const float* __restrict__ Wp,
                                                  const float* __restrict__ bp,
                                                  float* __restrict__ outp) {
    __shared__ float s_m[CH];
    int g = blockIdx.x, c = threadIdx.x;

    float acc = 0.0f;
#pragma unroll
    for (int r = 0; r < NREP; ++r)
        acc += gsums[(size_t)r * (NUM_G * CH) + g * CH + c];

    float inv = 1.0f / fmaxf((float)counts[g], 1.0f);
    s_m[c] = acc * inv;
    __syncthreads();

    if (c < OUT_CH) {
        float o = bp[c];
        for (int k = 0; k < CH; ++k)
            o = fmaf(s_m[k], Wp[k * OUT_CH + c], o);
        outp[g * OUT_CH + c] = o;
    }
}

extern "C" void kernel_launch(void* const* d_in, const int* in_sizes, int n_in,
                              void* d_out, int out_size, void* d_ws, size_t ws_size,
                              hipStream_t stream) {
    (void)in_sizes; (void)n_in; (void)out_size; (void)ws_size;
    const float* x     = (const float*)d_in[0];
    const int*   ei    = (const int*)d_in[1];
    const int*   batch = (const int*)d_in[2];
    const float* W1 = (const float*)d_in[3];
    const float* b1 = (const float*)d_in[4];
    const float* W2 = (const float*)d_in[5];
    const float* b2 = (const float*)d_in[6];
    const float* W3 = (const float*)d_in[7];
    const float* b3 = (const float*)d_in[8];
    const float* Wp = (const float*)d_in[9];
    const float* bp = (const float*)d_in[10];
    float* outp = (float*)d_out;

    const int* srcp = ei;
    const int* dstp = ei + N_EDGES;

    char* ws = (char*)d_ws;
    auto carve = [&](size_t bytes) {
        char* p = ws;
        ws += (bytes + 255) & ~(size_t)255;
        return p;
    };
    ushort_t* Hb = (ushort_t*)carve((size_t)N_NODES * CH * 2);  // 25.6 MB
    ushort_t* Ab = (ushort_t*)carve((size_t)N_NODES * CH * 2);  // 25.6 MB
    ushort_t* Wt1 = (ushort_t*)carve((size_t)CH * CH * 2);
    ushort_t* Wt2 = (ushort_t*)carve((size_t)CH * CH * 2);
    ushort_t* Wt3 = (ushort_t*)carve((size_t)CH * CH * 2);
    int*   csr_src  = (int*)carve((size_t)N_EDGES * 4);
    int*   pos      = (int*)carve((size_t)N_EDGES * 4);
    int*   cnt8     = (int*)carve((size_t)NREP * N_NODES * 4);  // 3.2 MB
    int*   ptrA     = (int*)carve((size_t)(N_NODES + 1) * 4);
    float* dinv     = (float*)carve((size_t)N_NODES * 4);
    int*   bsum     = (int*)carve((size_t)SB * 4);
    int*   boff     = (int*)carve((size_t)SB * 4);
    float* gsums    = (float*)carve((size_t)NREP * NUM_G * CH * 4);  // 256 KB
    int*   counts   = (int*)carve((size_t)NUM_G * 4);

    hipMemsetAsync(cnt8,   0, (size_t)NREP * N_NODES * 4, stream);
    hipMemsetAsync(gsums,  0, (size_t)NREP * NUM_G * CH * 4, stream);
    hipMemsetAsync(counts, 0, (size_t)NUM_G * 4, stream);

    prep_kernel<<<EB + 3 * WB, 256, 0, stream>>>(W1, W2, W3, Wt1, Wt2, Wt3,
                                                 dstp, cnt8, pos);
    scan_p1<<<SB, 1024, 0, stream>>>(cnt8, ptrA, bsum, dinv, batch, counts);
    scan_p2<<<1, 128, 0, stream>>>(bsum, boff, ptrA);
    scan_p3<<<SB, 1024, 0, stream>>>(ptrA, boff, cnt8);

    // layer 1 GEMM (fp32 A, in-register bf16 cvt) overlapped with CSR fill
    fill_gemm1<<<EB8 + GB, 256, 0, stream>>>(srcp, dstp, pos, cnt8, csr_src,
                                             x, Wt1, b1, Hb);
    agg_bf16 <<<AB2, 256, 0, stream>>>(Hb, csr_src, ptrA, dinv, Ab);
    // layer 2
    gemm_mfma<<<GB2, 512, 0, stream>>>(Ab, Wt2, b2, Hb);
    agg_bf16 <<<AB2, 256, 0, stream>>>(Hb, csr_src, ptrA, dinv, Ab);
    // layer 3: GEMM then aggregation fused with pooling (replica atomics)
    gemm_mfma<<<GB2, 512, 0, stream>>>(Ab, Wt3, b3, Hb);
    agg_pool <<<AB2, 256, 0, stream>>>(Hb, csr_src, ptrA, dinv, batch, gsums);

    out_kernel<<<NUM_G, 128, 0, stream>>>(gsums, counts, Wp, bp, outp);
}

// Round 8
// 515.595 us; speedup vs baseline: 1.0750x; 1.0750x over previous
//
#include <hip/hip_runtime.h>

#define N_NODES 100000
#define N_EDGES 1600000
#define CH      128
#define OUT_CH  64
#define NUM_G   64
#define NREP    8           // replicas (XCD-aligned via blockIdx&7)

typedef unsigned short ushort_t;
typedef unsigned int uint_t;
typedef __attribute__((ext_vector_type(8))) short short8;
typedef __attribute__((ext_vector_type(4))) float f32x4;

#define WB 64               // cvt_w blocks per weight (128*128/256)
#define EB 6250             // edge blocks, 1 edge/thread (prep)
#define EB8 782             // edge blocks, 8 edges/thread (fill)
#define GB ((N_NODES + 63) / 64)     // gemm1 row-blocks (64 rows/block)
#define GB2 ((N_NODES + 127) / 128)  // lds-gemm row-blocks (128 rows/block)
#define AB ((N_NODES + 3) / 4)       // agg node-quads (4 nodes/block)
#define AB2 (AB * 2)                 // channel-split agg_pool blocks
#define SB 98               // scan blocks (ceil(100000/1024))

__device__ __forceinline__ ushort_t f2b(float f) {
    union { float f; uint_t i; } v; v.f = f;
    uint_t u = v.i;
    uint_t r = (u + 0x7fffu + ((u >> 16) & 1u)) >> 16;
    return (ushort_t)r;
}
__device__ __forceinline__ float blo(uint_t u) {
    union { uint_t i; float f; } v; v.i = u << 16; return v.f;
}
__device__ __forceinline__ float bhi(uint_t u) {
    union { uint_t i; float f; } v; v.i = u & 0xffff0000u; return v.f;
}

// ---------------- tiny pre-kernel: W1/W2/W3 f32 -> bf16 transposed -----------
__global__ __launch_bounds__(256) void cvtw_kernel(const float* __restrict__ W1,
                                                   const float* __restrict__ W2,
                                                   const float* __restrict__ W3,
                                                   ushort_t* __restrict__ Wt1,
                                                   ushort_t* __restrict__ Wt2,
                                                   ushort_t* __restrict__ Wt3) {
    int wi = blockIdx.x / WB;
    const float* W  = (wi == 0) ? W1 : (wi == 1) ? W2 : W3;
    ushort_t*   Wt = (wi == 0) ? Wt1 : (wi == 1) ? Wt2 : Wt3;
    int t = (blockIdx.x % WB) * 256 + threadIdx.x;
    int k = t >> 7, n = t & 127;
    Wt[(size_t)n * CH + k] = f2b(W[t]);
}

// ---------------- 3-phase scan (+dinv + replica fold + graph counts) ---------
__device__ __forceinline__ int wave_incl_scan(int v, int lane) {
#pragma unroll
    for (int off = 1; off < 64; off <<= 1) {
        int t = __shfl_up(v, off);
        if (lane >= off) v += t;
    }
    return v;
}

__global__ __launch_bounds__(1024) void scan_p1(int* __restrict__ cnt8,
                                                int* __restrict__ ptr,
                                                int* __restrict__ bsum,
                                                float* __restrict__ dinv,
                                                const int* __restrict__ batch,
                                                int* __restrict__ counts) {
    __shared__ int s_w[16];
    __shared__ int s_c[NUM_G];
    int tid = threadIdx.x, lane = tid & 63, wid = tid >> 6;
    int i = blockIdx.x * 1024 + tid;
    int v = 0;
    if (i < N_NODES) {
        // fold 8 replicas -> total; store per-replica EXCLUSIVE offsets in place
        int run = 0;
#pragma unroll
        for (int r = 0; r < NREP; ++r) {
            size_t idx = (size_t)r * N_NODES + i;
            int t = cnt8[idx];
            cnt8[idx] = run;
            run += t;
        }
        v = run;
        dinv[i] = rsqrtf((float)v + 1.0f);
    }
    int incl = wave_incl_scan(v, lane);
    if (lane == 63) s_w[wid] = incl;
    if (tid < NUM_G) s_c[tid] = 0;
    __syncthreads();
    if (tid < 16) {
        int w = s_w[tid];
#pragma unroll
        for (int off = 1; off < 16; off <<= 1) {
            int t = __shfl_up(w, off);
            if (tid >= off) w += t;
        }
        s_w[tid] = w;
    }
    if (i < N_NODES) atomicAdd(&s_c[batch[i]], 1);   // graph-size histogram
    __syncthreads();
    int woff = (wid > 0) ? s_w[wid - 1] : 0;
    if (i < N_NODES) ptr[i] = woff + incl - v;     // block-local exclusive
    if (tid == 0) bsum[blockIdx.x] = s_w[15];
    if (tid < NUM_G) atomicAdd(&counts[tid], s_c[tid]);
}

__global__ __launch_bounds__(128) void scan_p2(const int* __restrict__ bsum,
                                               int* __restrict__ boff,
                                               int* __restrict__ ptr) {
    __shared__ int s_w[2];
    int tid = threadIdx.x, lane = tid & 63, wid = tid >> 6;
    int v = (tid < SB) ? bsum[tid] : 0;
    int incl = wave_incl_scan(v, lane);
    if (lane == 63) s_w[wid] = incl;
    __syncthreads();
    int woff = (wid == 1) ? s_w[0] : 0;
    int excl = woff + incl - v;
    if (tid < SB) boff[tid] = excl;
    if (tid == SB - 1) ptr[N_NODES] = excl + v;
}

// phase 3: finalize ptr AND fold final ptr into every cnt8 replica, so the
// fill kernel needs a single random read (cnt8[r][d] = ptr_final[d]+excl_r[d]).
__global__ __launch_bounds__(1024) void scan_p3(int* __restrict__ ptr,
                                                const int* __restrict__ boff,
                                                int* __restrict__ cnt8) {
    int i = blockIdx.x * 1024 + threadIdx.x;
    if (i < N_NODES) {
        int fp = ptr[i] + boff[blockIdx.x];
        ptr[i] = fp;
#pragma unroll
        for (int r = 0; r < NREP; ++r)
            cnt8[(size_t)r * N_NODES + i] += fp;
    }
}

// ---------------- MFMA GEMM body, global-Wt flavor --------------------------
template <bool F32A>
__device__ __forceinline__ void gemm_body(int bid, int tid,
                                          const void* __restrict__ A,
                                          const ushort_t* __restrict__ Wt,
                                          const float* __restrict__ bias,
                                          ushort_t* __restrict__ H) {
    int wv = tid >> 6, lane = tid & 63;
    int q = lane >> 4, ml = lane & 15;
    int r0 = bid * 64 + wv * 16;
    int arow = r0 + ml;
    if (arow >= N_NODES) arow = N_NODES - 1;  // clamp; stores guarded

    f32x4 acc[8];
#pragma unroll
    for (int ct = 0; ct < 8; ++ct) { acc[ct][0] = 0.f; acc[ct][1] = 0.f; acc[ct][2] = 0.f; acc[ct][3] = 0.f; }

#pragma unroll
    for (int ks = 0; ks < 4; ++ks) {
        short8 af;
        if constexpr (F32A) {
            const float* ap = (const float*)A + (size_t)arow * CH + ks * 32 + q * 8;
            f32x4 v0 = *(const f32x4*)ap;
            f32x4 v1 = *(const f32x4*)(ap + 4);
#pragma unroll
            for (int j = 0; j < 4; ++j) {
                af[j]     = (short)f2b(v0[j]);
                af[j + 4] = (short)f2b(v1[j]);
            }
        } else {
            const ushort_t* ap = (const ushort_t*)A + (size_t)arow * CH + ks * 32 + q * 8;
            af = *(const short8*)ap;
        }
#pragma unroll
        for (int ct = 0; ct < 8; ++ct) {
            short8 bf = *(const short8*)(Wt + (size_t)(ct * 16 + ml) * CH + ks * 32 + q * 8);
            acc[ct] = __builtin_amdgcn_mfma_f32_16x16x32_bf16(af, bf, acc[ct], 0, 0, 0);
        }
    }

#pragma unroll
    for (int ct = 0; ct < 8; ++ct) {
        int col = ct * 16 + ml;
        float bv = bias[col];
#pragma unroll
        for (int i = 0; i < 4; ++i) {
            int rr = r0 + q * 4 + i;
            if (rr < N_NODES)
                H[(size_t)rr * CH + col] = f2b(acc[ct][i] + bv);
        }
    }
}

// ---------------- fused: degree-count atomics | gemm layer-1 (fp32 A) --------
// The ~90us serial atomic pass now hides under the layer-1 MFMA (which only
// needs x and Wt1). Replica r = blockIdx&7 == (e>>8)&7, matching fill_kernel.
__global__ __launch_bounds__(256) void prep_gemm1(const int* __restrict__ dst,
                                                  int* __restrict__ cnt8,
                                                  int* __restrict__ pos,
                                                  const float* __restrict__ x,
                                                  const ushort_t* __restrict__ Wt,
                                                  const float* __restrict__ bias,
                                                  ushort_t* __restrict__ H) {
    if (blockIdx.x < EB) {
        int e = blockIdx.x * 256 + threadIdx.x;   // EB*256 == N_EDGES exactly
        int r = blockIdx.x & (NREP - 1);
        pos[e] = atomicAdd(&cnt8[(size_t)r * N_NODES + dst[e]], 1);
    } else {
        gemm_body<true>(blockIdx.x - EB, threadIdx.x, x, Wt, bias, H);
    }
}

// ---------------- CSR fill, scatter only (8 edges/thread) --------------------
__global__ __launch_bounds__(256) void fill_kernel(const int* __restrict__ src,
                                                   const int* __restrict__ dst,
                                                   const int* __restrict__ pos,
                                                   const int* __restrict__ cnt8,
                                                   int* __restrict__ csr_src) {
    int e = (blockIdx.x * 256 + threadIdx.x) * 8;
    if (e < N_EDGES) {     // N_EDGES % 8 == 0; 8-aligned e never crosses 256
        const int* base = cnt8 + (size_t)((e >> 8) & (NREP - 1)) * N_NODES;
        int4 da = *(const int4*)(dst + e);
        int4 db = *(const int4*)(dst + e + 4);
        int4 pa = *(const int4*)(pos + e);
        int4 pb = *(const int4*)(pos + e + 4);
        int4 sa = *(const int4*)(src + e);
        int4 sb = *(const int4*)(src + e + 4);
        csr_src[base[da.x] + pa.x] = sa.x;
        csr_src[base[da.y] + pa.y] = sa.y;
        csr_src[base[da.z] + pa.z] = sa.z;
        csr_src[base[da.w] + pa.w] = sa.w;
        csr_src[base[db.x] + pb.x] = sb.x;
        csr_src[base[db.y] + pb.y] = sb.y;
        csr_src[base[db.z] + pb.z] = sb.z;
        csr_src[base[db.w] + pb.w] = sb.w;
    }
}

// ---------------- standalone GEMM: Wt staged in LDS (XOR-swizzled) -----------
__global__ __launch_bounds__(512) void gemm_mfma(const ushort_t* __restrict__ A,
                                                 const ushort_t* __restrict__ Wt,
                                                 const float* __restrict__ bias,
                                                 ushort_t* __restrict__ H) {
    __shared__ ushort_t sW[CH * CH];   // 32 KiB
    int tid = threadIdx.x;
    for (int i = tid; i < CH * CH / 8; i += 512) {   // 2048 x 16B chunks
        int row = i >> 4, slot = i & 15;
        uint4 v = *(const uint4*)(Wt + (size_t)row * CH + slot * 8);
        *(uint4*)(&sW[row * CH + ((slot ^ (row & 7)) * 8)]) = v;
    }
    __syncthreads();

    int wv = tid >> 6, lane = tid & 63;
    int q = lane >> 4, ml = lane & 15;
    int r0 = blockIdx.x * 128 + wv * 16;
    int arow = r0 + ml;
    if (arow >= N_NODES) arow = N_NODES - 1;
    const ushort_t* ap = A + (size_t)arow * CH;

    f32x4 acc[8];
#pragma unroll
    for (int ct = 0; ct < 8; ++ct) { acc[ct][0] = 0.f; acc[ct][1] = 0.f; acc[ct][2] = 0.f; acc[ct][3] = 0.f; }

#pragma unroll
    for (int ks = 0; ks < 4; ++ks) {
        short8 af = *(const short8*)(ap + ks * 32 + q * 8);
        int slot = ks * 4 + q;
#pragma unroll
        for (int ct = 0; ct < 8; ++ct) {
            int srow = ct * 16 + ml;
            short8 bf = *(const short8*)(&sW[srow * CH + ((slot ^ (srow & 7)) * 8)]);
            acc[ct] = __builtin_amdgcn_mfma_f32_16x16x32_bf16(af, bf, acc[ct], 0, 0, 0);
        }
    }

#pragma unroll
    for (int ct = 0; ct < 8; ++ct) {
        int col = ct * 16 + ml;
        float bv = bias[col];
#pragma unroll
        for (int i = 0; i < 4; ++i) {
            int rr = r0 + q * 4 + i;
            if (rr < N_NODES)
                H[(size_t)rr * CH + col] = f2b(acc[ct][i] + bv);
        }
    }
}

// ---------------- UNSPLIT gather body (software-pipelined, 2-deep) -----------
// acc = dn*(sum_e dinv[s]*h[s] + dn*h[n]). 16-lane channel groups x 4 edge
// slots; next quad's rows prefetched while current is FMA'd.
__device__ __forceinline__ void agg_node(int node, int lane, int q, int c8,
                                         const ushort_t* __restrict__ h,
                                         const int* __restrict__ csr_src,
                                         const int* __restrict__ ptr,
                                         const float* __restrict__ dinv,
                                         float (&acc)[8]) {
    int beg = ptr[node], end = ptr[node + 1];
    float dn = dinv[node];
    uint4 us = *(const uint4*)(h + (size_t)node * CH + c8);   // early self load
#pragma unroll
    for (int i = 0; i < 8; ++i) acc[i] = 0.0f;

    for (int e0 = beg; e0 < end; e0 += 64) {
        int e = e0 + lane;
        int s = 0; float w = 0.0f;
        if (e < end) { s = csr_src[e]; w = dinv[s]; }
        int m = min(64, end - e0);

        int   sj = __shfl(s, q);
        float wj = __shfl(w, q);
        uint4 u  = *(const uint4*)(h + (size_t)sj * CH + c8);

        for (int j0 = 0; j0 < m; j0 += 4) {
            uint4 un = u; float wn = 0.0f;
            if (j0 + 4 < m) {
                int sn = __shfl(s, j0 + 4 + q);
                wn = __shfl(w, j0 + 4 + q);
                un = *(const uint4*)(h + (size_t)sn * CH + c8);
            }
            acc[0] = fmaf(wj, blo(u.x), acc[0]);
            acc[1] = fmaf(wj, bhi(u.x), acc[1]);
            acc[2] = fmaf(wj, blo(u.y), acc[2]);
            acc[3] = fmaf(wj, bhi(u.y), acc[3]);
            acc[4] = fmaf(wj, blo(u.z), acc[4]);
            acc[5] = fmaf(wj, bhi(u.z), acc[5]);
            acc[6] = fmaf(wj, blo(u.w), acc[6]);
            acc[7] = fmaf(wj, bhi(u.w), acc[7]);
            u = un; wj = wn;
        }
    }

#pragma unroll
    for (int i = 0; i < 8; ++i) {
        acc[i] += __shfl_xor(acc[i], 16);
        acc[i] += __shfl_xor(acc[i], 32);
    }

    acc[0] = dn * fmaf(dn, blo(us.x), acc[0]);
    acc[1] = dn * fmaf(dn, bhi(us.x), acc[1]);
    acc[2] = dn * fmaf(dn, blo(us.y), acc[2]);
    acc[3] = dn * fmaf(dn, bhi(us.y), acc[3]);
    acc[4] = dn * fmaf(dn, blo(us.z), acc[4]);
    acc[5] = dn * fmaf(dn, bhi(us.z), acc[5]);
    acc[6] = dn * fmaf(dn, blo(us.w), acc[6]);
    acc[7] = dn * fmaf(dn, bhi(us.w), acc[7]);
}

// ---------------- edge aggregation, layers 1&2 (UNSPLIT; bf16 + relu) --------
// Per-node fixed costs (~50% of work at avg deg 16) paid ONCE per node --
// the channel-split variant doubled them for zero atomic benefit (r7).
__global__ __launch_bounds__(256) void agg_bf16(const ushort_t* __restrict__ h,
                                                const int* __restrict__ csr_src,
                                                const int* __restrict__ ptr,
                                                const float* __restrict__ dinv,
                                                ushort_t* __restrict__ outp) {
    int wv = threadIdx.x >> 6, lane = threadIdx.x & 63;
    int node = blockIdx.x * 4 + wv;
    if (node >= N_NODES) return;
    int q = lane >> 4;
    int c8 = (lane & 15) * 8;

    float acc[8];
    agg_node(node, lane, q, c8, h, csr_src, ptr, dinv, acc);

#pragma unroll
    for (int i = 0; i < 8; ++i) acc[i] = fmaxf(acc[i], 0.0f);   // relu

    if (q == 0) {
        uint4 o;
        o.x = (uint_t)f2b(acc[0]) | ((uint_t)f2b(acc[1]) << 16);
        o.y = (uint_t)f2b(acc[2]) | ((uint_t)f2b(acc[3]) << 16);
        o.z = (uint_t)f2b(acc[4]) | ((uint_t)f2b(acc[5]) << 16);
        o.w = (uint_t)f2b(acc[6]) | ((uint_t)f2b(acc[7]) << 16);
        *(uint4*)(outp + (size_t)node * CH + c8) = o;
    }
}

// ---------------- channel-split gather body (agg_pool only) ------------------
// 8-lane channel groups x 8 edge slots; cb = half*64 + (lane&7)*8, cg=lane>>3.
__device__ __forceinline__ void agg_node_h(int node, int lane, int cg, int cb,
                                           const ushort_t* __restrict__ h,
                                           const int* __restrict__ csr_src,
                                           const int* __restrict__ ptr,
                                           const float* __restrict__ dinv,
                                           float (&acc)[8]) {
    int beg = ptr[node], end = ptr[node + 1];
    float dn = dinv[node];
    uint4 us = *(const uint4*)(h + (size_t)node * CH + cb);   // early self load
#pragma unroll
    for (int i = 0; i < 8; ++i) acc[i] = 0.0f;

    for (int e0 = beg; e0 < end; e0 += 64) {
        int e = e0 + lane;
        int s = 0; float w = 0.0f;
        if (e < end) { s = csr_src[e]; w = dinv[s]; }
        int m = min(64, end - e0);

        int   sj = __shfl(s, cg);
        float wj = __shfl(w, cg);
        uint4 u  = *(const uint4*)(h + (size_t)sj * CH + cb);

        for (int j0 = 0; j0 < m; j0 += 8) {
            uint4 un = u; float wn = 0.0f;
            if (j0 + 8 < m) {                      // max shfl idx 56+7=63, safe
                int sn = __shfl(s, j0 + 8 + cg);
                wn = __shfl(w, j0 + 8 + cg);
                un = *(const uint4*)(h + (size_t)sn * CH + cb);
            }
            acc[0] = fmaf(wj, blo(u.x), acc[0]);
            acc[1] = fmaf(wj, bhi(u.x), acc[1]);
            acc[2] = fmaf(wj, blo(u.y), acc[2]);
            acc[3] = fmaf(wj, bhi(u.y), acc[3]);
            acc[4] = fmaf(wj, blo(u.z), acc[4]);
            acc[5] = fmaf(wj, bhi(u.z), acc[5]);
            acc[6] = fmaf(wj, blo(u.w), acc[6]);
            acc[7] = fmaf(wj, bhi(u.w), acc[7]);
            u = un; wj = wn;
        }
    }

#pragma unroll
    for (int i = 0; i < 8; ++i) {          // sum over the 8 edge-slot groups
        acc[i] += __shfl_xor(acc[i], 8);
        acc[i] += __shfl_xor(acc[i], 16);
        acc[i] += __shfl_xor(acc[i], 32);
    }

    acc[0] = dn * fmaf(dn, blo(us.x), acc[0]);
    acc[1] = dn * fmaf(dn, bhi(us.x), acc[1]);
    acc[2] = dn * fmaf(dn, blo(us.y), acc[2]);
    acc[3] = dn * fmaf(dn, bhi(us.y), acc[3]);
    acc[4] = dn * fmaf(dn, blo(us.z), acc[4]);
    acc[5] = dn * fmaf(dn, bhi(us.z), acc[5]);
    acc[6] = dn * fmaf(dn, blo(us.w), acc[6]);
    acc[7] = dn * fmaf(dn, bhi(us.w), acc[7]);
}

__device__ __forceinline__ void split_decode(int b, int wv,
                                             int& half, int& node) {
    half = (b >> 2) & 1;
    int nb = ((b >> 3) << 2) | (b & 3);     // [0, AB)
    node = nb * 4 + wv;
}

// ---------------- layer-3 aggregation fused with mean-pool (SPLIT) -----------
// Kept from r7: the 1-atomic-instr/wave layout (64 atomics spanning 2 cache
// lines) halves atomic traffic 100->50 MB; measured 107->96us.
__global__ __launch_bounds__(256) void agg_pool(const ushort_t* __restrict__ h,
                                                const int* __restrict__ csr_src,
                                                const int* __restrict__ ptr,
                                                const float* __restrict__ dinv,
                                                const int* __restrict__ batch,
                                                float* __restrict__ gsums) {
    int wv = threadIdx.x >> 6, lane = threadIdx.x & 63;
    int half, node;
    split_decode(blockIdx.x, wv, half, node);
    if (node >= N_NODES) return;
    int cg = lane >> 3;
    int cb = half * 64 + (lane & 7) * 8;

    float acc[8];
    agg_node_h(node, lane, cg, cb, h, csr_src, ptr, dinv, acc);  // no relu

    // static-index select of acc[cg] (avoid runtime-indexed array -> scratch)
    float val = acc[0];
#pragma unroll
    for (int t = 1; t < 8; ++t) if (cg == t) val = acc[t];

    int g = batch[node];
    unsafeAtomicAdd(gsums + (size_t)(blockIdx.x & (NREP - 1)) * (NUM_G * CH)
                          + g * CH + cb + cg, val);
}

// ---------------- final: fold 8 replicas, mean, @ Wp + bp --------------------
__global__ __launch_bounds__(128) void out_kernel(const float* __restrict__ gsums,
                                                  const int* __restrict__ counts,
                                                  const float* __restrict__ Wp,
                                                  const float* __restrict__ bp,
                                                  float* __restrict__ outp) {
    __shared__ float s_m[CH];
    int g = blockIdx.x, c = threadIdx.x;

    float acc = 0.0f;
#pragma unroll
    for (int r = 0; r < NREP; ++r)
        acc += gsums[(size_t)r * (NUM_G * CH) + g * CH + c];

    float inv = 1.0f / fmaxf((float)counts[g], 1.0f);
    s_m[c] = acc * inv;
    __syncthreads();

    if (c < OUT_CH) {
        float o = bp[c];
        for (int k = 0; k < CH; ++k)
            o = fmaf(s_m[k], Wp[k * OUT_CH + c], o);
        outp[g * OUT_CH + c] = o;
    }
}

extern "C" void kernel_launch(void* const* d_in, const int* in_sizes, int n_in,
                              void* d_out, int out_size, void* d_ws, size_t ws_size,
                              hipStream_t stream) {
    (void)in_sizes; (void)n_in; (void)out_size; (void)ws_size;
    const float* x     = (const float*)d_in[0];
    const int*   ei    = (const int*)d_in[1];
    const int*   batch = (const int*)d_in[2];
    const float* W1 = (const float*)d_in[3];
    const float* b1 = (const float*)d_in[4];
    const float* W2 = (const float*)d_in[5];
    const float* b2 = (const float*)d_in[6];
    const float* W3 = (const float*)d_in[7];
    const float* b3 = (const float*)d_in[8];
    const float* Wp = (const float*)d_in[9];
    const float* bp = (const float*)d_in[10];
    float* outp = (float*)d_out;

    const int* srcp = ei;
    const int* dstp = ei + N_EDGES;

    char* ws = (char*)d_ws;
    auto carve = [&](size_t bytes) {
        char* p = ws;
        ws += (bytes + 255) & ~(size_t)255;
        return p;
    };
    ushort_t* Hb = (ushort_t*)carve((size_t)N_NODES * CH * 2);  // 25.6 MB
    ushort_t* Ab = (ushort_t*)carve((size_t)N_NODES * CH * 2);  // 25.6 MB
    ushort_t* Wt1 = (ushort_t*)carve((size_t)CH * CH * 2);
    ushort_t* Wt2 = (ushort_t*)carve((size_t)CH * CH * 2);
    ushort_t* Wt3 = (ushort_t*)carve((size_t)CH * CH * 2);
    int*   csr_src  = (int*)carve((size_t)N_EDGES * 4);
    int*   pos      = (int*)carve((size_t)N_EDGES * 4);
    int*   cnt8     = (int*)carve((size_t)NREP * N_NODES * 4);  // 3.2 MB
    int*   ptrA     = (int*)carve((size_t)(N_NODES + 1) * 4);
    float* dinv     = (float*)carve((size_t)N_NODES * 4);
    int*   bsum     = (int*)carve((size_t)SB * 4);
    int*   boff     = (int*)carve((size_t)SB * 4);
    float* gsums    = (float*)carve((size_t)NREP * NUM_G * CH * 4);  // 256 KB
    int*   counts   = (int*)carve((size_t)NUM_G * 4);

    hipMemsetAsync(cnt8,   0, (size_t)NREP * N_NODES * 4, stream);
    hipMemsetAsync(gsums,  0, (size_t)NREP * NUM_G * CH * 4, stream);
    hipMemsetAsync(counts, 0, (size_t)NUM_G * 4, stream);

    // W conversions first (Wt1 needed by prep_gemm1's GEMM half)
    cvtw_kernel<<<3 * WB, 256, 0, stream>>>(W1, W2, W3, Wt1, Wt2, Wt3);

    // degree-count atomics overlapped with layer-1 GEMM (fp32 A, in-reg cvt)
    prep_gemm1<<<EB + GB, 256, 0, stream>>>(dstp, cnt8, pos, x, Wt1, b1, Hb);

    scan_p1<<<SB, 1024, 0, stream>>>(cnt8, ptrA, bsum, dinv, batch, counts);
    scan_p2<<<1, 128, 0, stream>>>(bsum, boff, ptrA);
    scan_p3<<<SB, 1024, 0, stream>>>(ptrA, boff, cnt8);

    // CSR scatter (standalone now)
    fill_kernel<<<EB8, 256, 0, stream>>>(srcp, dstp, pos, cnt8, csr_src);

    agg_bf16 <<<AB, 256, 0, stream>>>(Hb, csr_src, ptrA, dinv, Ab);
    // layer 2
    gemm_mfma<<<GB2, 512, 0, stream>>>(Ab, Wt2, b2, Hb);
    agg_bf16 <<<AB, 256, 0, stream>>>(Hb, csr_src, ptrA, dinv, Ab);
    // layer 3: GEMM then aggregation fused with pooling (split, replica atomics)
    gemm_mfma<<<GB2, 512, 0, stream>>>(Ab, Wt3, b3, Hb);
    agg_pool <<<AB2, 256, 0, stream>>>(Hb, csr_src, ptrA, dinv, batch, gsums);

    out_kernel<<<NUM_G, 128, 0, stream>>>(gsums, counts, Wp, bp, outp);
}